// Round 10
// baseline (408.738 us; speedup 1.0000x reference)
//
#include <hip/hip_runtime.h>
#include <hip/hip_bf16.h>

typedef __hip_bfloat16 bf16;
typedef __attribute__((ext_vector_type(8))) short short8v;
typedef __attribute__((ext_vector_type(4))) short short4v;
typedef __attribute__((ext_vector_type(4))) float f32x4;

__device__ __forceinline__ float b2f(bf16 v){ return __bfloat162float(v); }
__device__ __forceinline__ bf16  f2b(float v){ return __float2bfloat16(v); }
__device__ __forceinline__ float su2f(short s){
    unsigned short us = (unsigned short)s;
    return __bfloat162float(*reinterpret_cast<bf16*>(&us));
}
__device__ __forceinline__ short f2s(float v){
    bf16 b = __float2bfloat16(v);
    return *reinterpret_cast<short*>(&b);
}
__device__ __forceinline__ float ldf(const void* t, size_t i, int isb){
    return isb ? b2f(((const bf16*)t)[i]) : ((const float*)t)[i];
}

constexpr int Bn = 8, CIN = 384, RESn = 28, Nn = 784, DHn = 1024;
constexpr int AST = 800;   // padded attn/vt K-stride (25*32)

// ---------------------------------------------------- async global->LDS 16B
__device__ __forceinline__ void gload16(const void* g, void* l)
{
    __builtin_amdgcn_global_load_lds(
        (const __attribute__((address_space(1))) void*)g,
        (__attribute__((address_space(3))) void*)l, 16, 0, 0);
}

// -------------------------------------------------- dtype detector (1 thread)
__global__ void k_detect(const unsigned* __restrict__ xw, int* __restrict__ flag)
{
    if (blockIdx.x == 0 && threadIdx.x == 0) {
        int cnt = 0;
        for (int i = 0; i < 256; ++i) {
            unsigned lo = xw[i] & 0xFFFFu;
            int e = (int)((lo >> 7) & 0xFF);
            if (e >= 112 && e <= 132) ++cnt;
        }
        *flag = (cnt >= 128) ? 1 : 0;
    }
}

// -- fused prep: wpack | affine | mixbias | dw-weight transpose (reads d_in raw)
struct PtrArgs { const void* p[26]; };
__global__ __launch_bounds__(256) void k_prep(PtrArgs a, bf16* __restrict__ Wqkv,
                                              float* __restrict__ al, float* __restrict__ be,
                                              float* __restrict__ mb, bf16* __restrict__ Wvlt,
                                              const int* __restrict__ flag)
{
    const int isb = *flag;
    const int tid = threadIdx.x;
    const int role = blockIdx.y;
    if (role == 0) {
        int stride = gridDim.x * 256;
        for (int e = blockIdx.x * 256 + tid; e < 1536 * 384; e += stride) {
            int co = e / 384, k = e % 384;
            const void* src; int lc;
            if (co < 256)      { src = a.p[1]; lc = co; }
            else if (co < 512) { src = a.p[5]; lc = co - 256; }
            else               { src = a.p[9]; lc = co - 512; }
            Wqkv[e] = f2b(ldf(src, (size_t)lc * 384 + k, isb));
        }
    } else if (role == 1) {
        int co = blockIdx.x * 256 + tid;
        if (co < 1536) {
            const void *b_, *s_, *h_; int lc;
            if (co < 256)      { b_ = a.p[2];  s_ = a.p[3];  h_ = a.p[4];  lc = co; }
            else if (co < 512) { b_ = a.p[6];  s_ = a.p[7];  h_ = a.p[8];  lc = co - 256; }
            else               { b_ = a.p[10]; s_ = a.p[11]; h_ = a.p[12]; lc = co - 512; }
            float aa = ldf(s_, lc, isb);
            al[co] = aa;
            be[co] = ldf(b_, lc, isb) * aa + ldf(h_, lc, isb);
        }
    } else if (role == 2) {
        int i = blockIdx.x * 256 + tid;
        if (i < 8 * Nn) {
            int g = i / Nn, p = i % Nn;
            float acc = ldf(a.p[18], g, isb);
            #pragma unroll
            for (int h = 0; h < 8; ++h)
                acc += ldf(a.p[17], g * 8 + h, isb) * ldf(a.p[25], (size_t)h * Nn + p, isb);
            mb[i] = acc;
        }
    } else {
        int e = blockIdx.x * 256 + tid;   // Wvl [1024][9] -> Wvlt [9][1024]
        if (e < 1024 * 9) {
            int c = e / 9, tap = e % 9;
            Wvlt[tap * 1024 + c] = f2b(ldf(a.p[13], e, isb));
        }
    }
}

// ------------------------------------- convert needed tensors -> bf16
struct ConvArgs { const void* src[10]; unsigned long long dstoff[10]; int n[10]; };
__global__ void k_convb_all(ConvArgs a, char* __restrict__ ws, const int* __restrict__ flag)
{
    int i = blockIdx.y;
    int n = a.n[i];
    const void* s = a.src[i];
    bf16* d = (bf16*)(ws + a.dstoff[i]);
    int isb = *flag;
    int stride = gridDim.x * blockDim.x;
    for (int t = blockIdx.x * blockDim.x + threadIdx.x; t < n; t += stride)
        d[t] = isb ? ((const bf16*)s)[t] : f2b(((const float*)s)[t]);
}

// ------------------- expand mb through idx: abfull[g][n][m] (b-independent)
__global__ __launch_bounds__(256) void k_abfull(
    const float* __restrict__ mb, const int* __restrict__ idxs,
    bf16* __restrict__ abfull)
{
    __shared__ float mbs[8][Nn];
    const int tid = threadIdx.x;
    for (int i = tid; i < 8 * Nn; i += 256) ((float*)mbs)[i] = mb[i];
    __syncthreads();
    const int nstart = blockIdx.x * 2;
    for (int n = nstart; n < nstart + 2; ++n) {
        for (int m = tid; m < Nn; m += 256) {
            int id = idxs[(size_t)n * Nn + m];
            #pragma unroll
            for (int g = 0; g < 8; ++g)
                abfull[((size_t)g * Nn + n) * AST + m] = f2b(mbs[g][id]);
        }
    }
}

// ------------- x transpose + inline convert: [b][384][784] -> [b][784][384]
__global__ __launch_bounds__(256) void k_xt(const void* __restrict__ xr, bf16* __restrict__ xt,
                                            const int* __restrict__ flag)
{
    const int isb = *flag;
    __shared__ bf16 t[32][33];
    int b = blockIdx.z, n0 = blockIdx.x * 32, c0 = blockIdx.y * 32;
    int tid = threadIdx.x;
    for (int i = tid; i < 1024; i += 256) {
        int r = i >> 5, c = i & 31;
        int n = n0 + c;
        t[r][c] = (n < Nn) ? f2b(ldf(xr, ((size_t)b * CIN + c0 + r) * Nn + n, isb)) : f2b(0.f);
    }
    __syncthreads();
    for (int i = tid; i < 1024; i += 256) {
        int r = i >> 5, c = i & 31;
        int n = n0 + r;
        if (n < Nn) xt[((size_t)b * Nn + n) * CIN + c0 + c] = t[c][r];
    }
}

// --------------------- v transpose: [n][c] -> [c][n] (stride AST, zero-padded)
__global__ __launch_bounds__(256) void k_vt(const bf16* __restrict__ vbuf, bf16* __restrict__ vt)
{
    __shared__ bf16 t[32][33];
    int b = blockIdx.z, n0 = blockIdx.x * 32, c0 = blockIdx.y * 32;
    int tid = threadIdx.x;
    for (int i = tid; i < 1024; i += 256) {
        int r = i >> 5, c = i & 31;
        int n = n0 + r;
        t[r][c] = (n < Nn) ? vbuf[((size_t)b * Nn + n) * DHn + c0 + c] : f2b(0.f);
    }
    __syncthreads();
    for (int i = tid; i < 1024; i += 256) {
        int r = i >> 5, c = i & 31;
        int n = n0 + c;   // n < 800 always (25*32 grid)
        vt[((size_t)b * DHn + c0 + r) * AST + n] = t[c][r];
    }
}

// -------------------- frag-linear staging: 64 rows x 32 k of a K-contig matrix
__device__ __forceinline__ void stage64x32(const bf16* __restrict__ src,
    int row0, int row_lim, int k0, int k_lim, int ld, short* lds, int tid)
{
    int rsub = ((tid >> 6) << 4) | (tid & 15);
    int q    = (tid >> 4) & 3;
    int row = row0 + rsub; row = row < row_lim ? row : row_lim - 1;
    gload16((const short*)src + (size_t)row * ld + k0 + q * 8,
            lds + (size_t)(((rsub >> 4) * 4 + q) * 16 + (rsub & 15)) * 8);
}

// ------------------- generic MFMA core: tile (MI*32) x 128, BK=32, gload_lds
template<int MI>
__device__ __forceinline__ void gemm_core(
    const bf16* __restrict__ A, int lda, int rowsA, int arow0,
    const bf16* __restrict__ B, int ldb, int rowsB, int brow0,
    int K, short* ldsA, short* ldsB, f32x4 (&acc)[MI][4])
{
    const int tid  = threadIdx.x;
    const int lane = tid & 63;
    const int wm   = tid >> 7, wn = (tid >> 6) & 1;
    const short8v* A8 = (const short8v*)ldsA;
    const short8v* B8 = (const short8v*)ldsB;

    for (int k0 = 0; k0 < K; k0 += 32) {
        __syncthreads();
        #pragma unroll
        for (int c = 0; c < MI / 2; ++c)
            stage64x32(A, arow0 + c * 64, rowsA, k0, K, lda, ldsA + c * 2048, tid);
        #pragma unroll
        for (int c = 0; c < 2; ++c)
            stage64x32(B, brow0 + c * 64, rowsB, k0, K, ldb, ldsB + c * 2048, tid);
        __syncthreads();
        short8v a[MI], bb[4];
        #pragma unroll
        for (int i = 0; i < MI; ++i) a[i] = A8[(wm * MI + i) * 64 + lane];
        #pragma unroll
        for (int j = 0; j < 4; ++j) bb[j] = B8[(wn * 4 + j) * 64 + lane];
        #pragma unroll
        for (int i = 0; i < MI; ++i)
            #pragma unroll
            for (int j = 0; j < 4; ++j)
                acc[i][j] = __builtin_amdgcn_mfma_f32_16x16x32_bf16(a[i], bb[j], acc[i][j], 0, 0, 0);
    }
}

#define EPI_COORDS(MI)                                      \
    const int tid  = threadIdx.x;                           \
    const int lane = tid & 63;                              \
    const int wm   = tid >> 7, wn = (tid >> 6) & 1;         \
    const int rq   = lane >> 4, cl = lane & 15; (void)rq;

// --------------------------------------------- q/k/v projection + BN (MFMA)
__global__ __launch_bounds__(256) void k_proj_m(
    const bf16* __restrict__ xt, const bf16* __restrict__ Wqkv,
    const float* __restrict__ al, const float* __restrict__ be,
    bf16* __restrict__ qbuf, bf16* __restrict__ kbuf, bf16* __restrict__ vbuf)
{
    __shared__ short ldsA[4096], ldsB[4096];
    const int n0 = blockIdx.x * 128, co0 = blockIdx.y * 128;
    const int b = blockIdx.z;
    f32x4 acc[4][4] = {};
    gemm_core<4>(xt + (size_t)b * Nn * CIN, CIN, Nn, n0,
                 Wqkv, CIN, 1536, co0, CIN, ldsA, ldsB, acc);
    EPI_COORDS(4)
    #pragma unroll
    for (int i = 0; i < 4; ++i)
        #pragma unroll
        for (int j = 0; j < 4; ++j) {
            int co = co0 + (wn * 4 + j) * 16 + cl;
            float a_ = al[co], bb_ = be[co];
            int nb = n0 + (wm * 4 + i) * 16 + rq * 4;
            #pragma unroll
            for (int r = 0; r < 4; ++r) {
                int n = nb + r;
                if (n >= Nn) continue;
                float y = a_ * acc[i][j][r] + bb_;
                if (co < 256)      qbuf[((size_t)b * Nn + n) * 256 + co]       = f2b(y);
                else if (co < 512) kbuf[((size_t)b * Nn + n) * 256 + (co-256)] = f2b(y);
                else               vbuf[((size_t)b * Nn + n) * DHn + (co-512)] = f2b(y);
            }
        }
}

// ---- attention A: per (16n, m-half) block: QK^T (MFMA) + th1 mix + exp -> E, sums
__global__ __launch_bounds__(256) void k_attA(
    const bf16* __restrict__ qbuf, const bf16* __restrict__ kbuf,
    const bf16* __restrict__ abfull, const bf16* __restrict__ W1,
    bf16* __restrict__ E, float* __restrict__ sums, int bi0)
{
    __shared__ short ldsQ[4096];        // 512 short8: q 16x256
    __shared__ short ldsK[16384];       // 2048 short8: k 64x256
    __shared__ float sred[4][8][16];
    __shared__ float w1s[64];
    const int tid = threadIdx.x;
    const int nt = blockIdx.x >> 1, ms = blockIdx.x & 1;
    const int bloc = blockIdx.y, b = bi0 + bloc;
    const int n0 = nt * 16;
    const int lane = tid & 63, wv = tid >> 6;
    const int qrow = lane >> 4, cl = lane & 15;

    if (tid < 64) w1s[tid] = b2f(W1[tid]) * 0.17677669529663687f;

    {   // stage q (frag layout): ldsQ8[(j>>2)*64 + (j&3)*16 + r] = q8[r*32+j]
        const short8v* q8 = (const short8v*)(qbuf + (size_t)b * Nn * 256);
        short8v* Q8w = (short8v*)ldsQ;
        #pragma unroll
        for (int s = tid; s < 512; s += 256) {
            int r = s >> 5, j = s & 31;
            Q8w[(j >> 2) * 64 + (j & 3) * 16 + r] = q8[(size_t)(n0 + r) * 32 + j];
        }
    }

    float sreg[8][4];
    #pragma unroll
    for (int g = 0; g < 8; ++g)
        #pragma unroll
        for (int r = 0; r < 4; ++r) sreg[g][r] = 0.f;

    const bf16* Bk = kbuf + (size_t)b * Nn * 256;
    const short8v* Q8 = (const short8v*)ldsQ;
    const short8v* K8 = (const short8v*)ldsK;
    const int nmt = 6 + ms;

    for (int mt = 0; mt < nmt; ++mt) {
        int m0 = ms * 384 + mt * 64;
        __syncthreads();
        #pragma unroll
        for (int h = 0; h < 8; ++h)
            stage64x32(Bk, m0, Nn, h * 32, 256, 256, ldsK + h * 2048, tid);
        __syncthreads();
        f32x4 acc[8];
        #pragma unroll
        for (int h = 0; h < 8; ++h) {
            short8v a = Q8[h * 64 + lane];
            short8v bb = K8[h * 256 + wv * 64 + lane];
            f32x4 z = {0.f, 0.f, 0.f, 0.f};
            acc[h] = __builtin_amdgcn_mfma_f32_16x16x32_bf16(a, bb, z, 0, 0, 0);
        }
        const int m = m0 + wv * 16 + cl;
        #pragma unroll
        for (int g = 0; g < 8; ++g) {
            #pragma unroll
            for (int r = 0; r < 4; ++r) {
                int n = n0 + qrow * 4 + r;
                float a = (m < AST) ?
                    su2f(*(const short*)&abfull[((size_t)g * Nn + n) * AST + m]) : 0.f;
                #pragma unroll
                for (int h = 0; h < 8; ++h) a += w1s[g * 8 + h] * acc[h][r];
                float e = (m < Nn) ? __expf(fminf(a, 60.f)) : 0.f;
                sreg[g][r] += e;
                if (m < AST)
                    E[((size_t)(bloc * 8 + g) * Nn + n) * AST + m] = f2b(e);
            }
        }
    }

    #pragma unroll
    for (int g = 0; g < 8; ++g)
        #pragma unroll
        for (int r = 0; r < 4; ++r) {
            float v = sreg[g][r];
            v += __shfl_xor(v, 1, 64);
            v += __shfl_xor(v, 2, 64);
            v += __shfl_xor(v, 4, 64);
            v += __shfl_xor(v, 8, 64);
            if (cl == 0) sred[wv][g][qrow * 4 + r] = v;
        }
    __syncthreads();
    if (tid < 128) {
        int g = tid >> 4, nl = tid & 15;
        float s = sred[0][g][nl] + sred[1][g][nl] + sred[2][g][nl] + sred[3][g][nl];
        sums[(size_t)ms * 64 * Nn + (size_t)(bloc * 8 + g) * Nn + n0 + nl] = s;
    }
}

// ---- attention B: per (32n, 2 out-heads) block: form P2 (th2+normalize) + PV MFMA
__global__ __launch_bounds__(256) void k_attB(
    const bf16* __restrict__ E, const float* __restrict__ sums,
    const bf16* __restrict__ vt, const bf16* __restrict__ W2,
    const bf16* __restrict__ b2v, bf16* __restrict__ obuf, int bi0)
{
    __shared__ short ldsP[2][2048];    // p2 32x64 per g'
    __shared__ short ldsV[2][8192];    // vt 128x64 per g'
    __shared__ float w2sh[2][8];
    __shared__ float b2sh[2];
    const int tid = threadIdx.x;
    const int nt = blockIdx.x, gp = blockIdx.y, bloc = blockIdx.z;
    const int b = bi0 + bloc;
    const int n0 = nt * 32;
    const int g0 = gp * 2;
    const int lane = tid & 63, wv = tid >> 6;

    if (tid < 16) w2sh[tid >> 3][tid & 7] = b2f(W2[(g0 + (tid >> 3)) * 8 + (tid & 7)]);
    if (tid < 2)  b2sh[tid] = b2f(b2v[g0 + tid]);

    const int nrow = tid >> 3;            // 0..31
    const int msg  = (tid & 7) * 8;       // m-local 0..56
    const int nclamp = (n0 + nrow < Nn) ? (n0 + nrow) : (Nn - 1);
    float dinv[8];
    #pragma unroll
    for (int h = 0; h < 8; ++h) {
        size_t idx = (size_t)(bloc * 8 + h) * Nn + nclamp;
        dinv[h] = 1.f / (sums[idx] + sums[(size_t)64 * Nn + idx]);
    }
    __syncthreads();

    f32x4 acc[2][2][2] = {};   // [g'sel][nsub][djj]

    for (int mt = 0; mt < 13; ++mt) {
        const int m0 = mt * 64;
        const int nks = (mt < 12) ? 2 : 1;
        __syncthreads();
        // stage vt for both g' (128 d-rows x nks*32 m)
        #pragma unroll
        for (int gs = 0; gs < 2; ++gs) {
            const bf16* vs = vt + ((size_t)b * DHn + (g0 + gs) * 128) * AST;
            for (int ks = 0; ks < nks; ++ks) {
                stage64x32(vs, 0,  128, m0 + ks * 32, AST, AST, ldsV[gs] + ks * 4096, tid);
                stage64x32(vs, 64, 128, m0 + ks * 32, AST, AST, ldsV[gs] + ks * 4096 + 2048, tid);
            }
        }
        // form P2 tiles (read E, scale by dinv, th2 mix)
        if (msg < nks * 32) {
            float p0[8], p1[8];
            #pragma unroll
            for (int e = 0; e < 8; ++e) { p0[e] = b2sh[0]; p1[e] = b2sh[1]; }
            #pragma unroll
            for (int g = 0; g < 8; ++g) {
                short8v ev = *(const short8v*)&E[
                    ((size_t)(bloc * 8 + g) * Nn + nclamp) * AST + m0 + msg];
                float w0 = w2sh[0][g], w1 = w2sh[1][g], dv = dinv[g];
                #pragma unroll
                for (int e = 0; e < 8; ++e) {
                    float pe = su2f(ev[e]) * dv;
                    p0[e] += w0 * pe;
                    p1[e] += w1 * pe;
                }
            }
            short8v s0, s1;
            #pragma unroll
            for (int e = 0; e < 8; ++e) { s0[e] = f2s(p0[e]); s1[e] = f2s(p1[e]); }
            int ks = msg >> 5, q = (msg >> 3) & 3, sub = nrow >> 4, r = nrow & 15;
            int slot = (ks * 2 + sub) * 64 + q * 16 + r;
            ((short8v*)ldsP[0])[slot] = s0;
            ((short8v*)ldsP[1])[slot] = s1;
        }
        __syncthreads();
        // PV MFMA
        #pragma unroll
        for (int gs = 0; gs < 2; ++gs)
            for (int ks = 0; ks < nks; ++ks)
                #pragma unroll
                for (int sub = 0; sub < 2; ++sub) {
                    short8v a = ((const short8v*)ldsP[gs])[(ks * 2 + sub) * 64 + lane];
                    #pragma unroll
                    for (int jj = 0; jj < 2; ++jj) {
                        short8v bb = ((const short8v*)ldsV[gs])[ks * 512 + (wv * 2 + jj) * 64 + lane];
                        acc[gs][sub][jj] =
                            __builtin_amdgcn_mfma_f32_16x16x32_bf16(a, bb, acc[gs][sub][jj], 0, 0, 0);
                    }
                }
    }

    const int qrow = lane >> 4, cl = lane & 15;
    #pragma unroll
    for (int gs = 0; gs < 2; ++gs)
        #pragma unroll
        for (int sub = 0; sub < 2; ++sub)
            #pragma unroll
            for (int jj = 0; jj < 2; ++jj) {
                int d = (g0 + gs) * 128 + (wv * 2 + jj) * 16 + cl;
                int nb = n0 + sub * 16 + qrow * 4;
                #pragma unroll
                for (int r = 0; r < 4; ++r) {
                    int n = nb + r;
                    if (n < Nn)
                        obuf[((size_t)b * Nn + n) * DHn + d] = f2b(acc[gs][sub][jj][r]);
                }
            }
}

// ---- depthwise conv+BN, ADDS into obuf (o += vl), fully vectorized weights
__global__ __launch_bounds__(256) void k_dwconv_add(
    const bf16* __restrict__ vbuf, const bf16* __restrict__ Wvlt,
    const bf16* __restrict__ bvl, const bf16* __restrict__ vls, const bf16* __restrict__ vlb,
    bf16* __restrict__ obuf)
{
    const int t = threadIdx.x;
    const int n = blockIdx.y * 2 + (t >> 7);
    const int bi = blockIdx.z;
    const int c0 = (t & 127) * 8;
    const int h = n / RESn, w = n % RESn;
    float acc[8] = {};
    #pragma unroll
    for (int dh = -1; dh <= 1; ++dh)
        #pragma unroll
        for (int dw = -1; dw <= 1; ++dw) {
            int hh = h + dh, ww = w + dw;
            if (hh < 0 || hh >= RESn || ww < 0 || ww >= RESn) continue;
            int widx = (dh + 1) * 3 + (dw + 1);
            short8v wv = *(const short8v*)&Wvlt[widx * 1024 + c0];
            short8v v  = *(const short8v*)&vbuf[((size_t)bi * Nn + hh * RESn + ww) * DHn + c0];
            #pragma unroll
            for (int u = 0; u < 8; ++u)
                acc[u] += su2f(wv[u]) * su2f(v[u]);
        }
    short8v bv = *(const short8v*)&bvl[c0];
    short8v sv = *(const short8v*)&vls[c0];
    short8v hv = *(const short8v*)&vlb[c0];
    size_t off = ((size_t)bi * Nn + n) * DHn + c0;
    short8v ov = *(short8v*)&obuf[off];
    short8v res;
    #pragma unroll
    for (int u = 0; u < 8; ++u) {
        float vl = su2f(sv[u]) * (acc[u] + su2f(bv[u])) + su2f(hv[u]);
        res[u] = f2s(su2f(ov[u]) + vl);
    }
    *(short8v*)&obuf[off] = res;
}

// --------------------------------------------- output projection + BN (MFMA)
__global__ __launch_bounds__(256) void k_outproj_m(
    const bf16* __restrict__ Wp, const bf16* __restrict__ obuf,
    const bf16* __restrict__ bp, const bf16* __restrict__ ps, const bf16* __restrict__ pb,
    void* __restrict__ outv, const int* __restrict__ flag)
{
    __shared__ short ldsA[2048], ldsB[4096];
    const int n0 = blockIdx.x * 128, oc0 = blockIdx.y * 64;
    const int b = blockIdx.z;
    f32x4 acc[2][4] = {};
    gemm_core<2>(Wp, DHn, 384, oc0,
                 obuf + (size_t)b * Nn * DHn, DHn, Nn, n0,
                 DHn, ldsA, ldsB, acc);
    const int isb = *flag;
    EPI_COORDS(2)
    #pragma unroll
    for (int i = 0; i < 2; ++i)
        #pragma unroll
        for (int j = 0; j < 4; ++j) {
            int n = n0 + (wn * 4 + j) * 16 + cl;
            if (n >= Nn) continue;
            int ocb = oc0 + (wm * 2 + i) * 16 + rq * 4;
            #pragma unroll
            for (int r = 0; r < 4; ++r) {
                int oc = ocb + r;
                float a_ = b2f(ps[oc]);
                float be_ = b2f(bp[oc]) * a_ + b2f(pb[oc]);
                float y = a_ * acc[i][j][r] + be_;
                size_t idx = ((size_t)b * CIN + oc) * Nn + n;
                if (isb) ((bf16*)outv)[idx] = f2b(y);
                else     ((float*)outv)[idx] = y;
            }
        }
}

extern "C" void kernel_launch(void* const* d_in, const int* in_sizes, int n_in,
                              void* d_out, int out_size, void* d_ws, size_t ws_size,
                              hipStream_t stream)
{
    char* ws = (char*)d_ws;
    auto align256 = [](size_t v) { return (v + 255) & ~(size_t)255; };

    size_t off = 0;
    size_t off_flag = off;            off = align256(off + 4);
    size_t p_off[26];
    for (int i = 0; i < 26; ++i) { p_off[i] = off; off = align256(off + (size_t)in_sizes[i] * 2); }
    size_t off_mb   = off; off = align256(off + (size_t)8 * Nn * 4);
    size_t off_ab   = off; off = align256(off + (size_t)8 * Nn * AST * 2);
    size_t off_q    = off; off = align256(off + (size_t)Bn * Nn * 256 * 2);
    size_t off_k    = off; off = align256(off + (size_t)Bn * Nn * 256 * 2);
    size_t off_v    = off; off = align256(off + (size_t)Bn * Nn * DHn * 2);
    size_t off_vt   = off; off = align256(off + (size_t)Bn * DHn * AST * 2);
    size_t off_o    = off; off = align256(off + (size_t)Bn * Nn * DHn * 2);
    size_t off_xt   = off; off = align256(off + (size_t)Bn * Nn * CIN * 2);
    size_t off_wqkv = off; off = align256(off + (size_t)1536 * CIN * 2);
    size_t off_al   = off; off = align256(off + (size_t)1536 * 4);
    size_t off_be   = off; off = align256(off + (size_t)1536 * 4);
    size_t off_wvlt = off; off = align256(off + (size_t)9 * 1024 * 2);
    size_t off_sums = off; off = align256(off + (size_t)2 * 64 * Nn * 4);
    size_t base = off;

    const size_t attn_per_b = (size_t)8 * Nn * AST * 2;
    int GB = 0;
    const int cand[4] = {8, 4, 2, 1};
    for (int ci = 0; ci < 4; ++ci) {
        if (base + (size_t)cand[ci] * attn_per_b + 512 <= ws_size) { GB = cand[ci]; break; }
    }
    if (!GB) return; // ws too small -> zeros out (diagnostic absmax ~17.4)

    size_t off_attn = base;

    int*  flag = (int*)(ws + off_flag);
    bf16* Pb[26];
    for (int i = 0; i < 26; ++i) Pb[i] = (bf16*)(ws + p_off[i]);
    float* mb    = (float*)(ws + off_mb);
    bf16* abfull = (bf16*)(ws + off_ab);
    bf16* qbuf  = (bf16*)(ws + off_q);
    bf16* kbuf  = (bf16*)(ws + off_k);
    bf16* vbuf  = (bf16*)(ws + off_v);
    bf16* vt    = (bf16*)(ws + off_vt);
    bf16* obuf  = (bf16*)(ws + off_o);
    bf16* xt    = (bf16*)(ws + off_xt);
    bf16* wqkv  = (bf16*)(ws + off_wqkv);
    float* alf  = (float*)(ws + off_al);
    float* bef  = (float*)(ws + off_be);
    bf16* wvlt  = (bf16*)(ws + off_wvlt);
    float* sums = (float*)(ws + off_sums);
    bf16* attn  = (bf16*)(ws + off_attn);
    const int* idxs = (const int*)d_in[26];

    k_detect<<<1, 64, 0, stream>>>((const unsigned*)d_in[0], flag);

    PtrArgs pa;
    for (int i = 0; i < 26; ++i) pa.p[i] = d_in[i];
    k_prep<<<dim3(288, 4), 256, 0, stream>>>(pa, wqkv, alf, bef, mb, wvlt, flag);

    const int cidx[10] = {14, 15, 16, 17, 19, 20, 21, 22, 23, 24};
    ConvArgs ca;
    for (int i = 0; i < 10; ++i) {
        ca.src[i] = d_in[cidx[i]];
        ca.dstoff[i] = p_off[cidx[i]];
        ca.n[i] = in_sizes[cidx[i]];
    }
    k_convb_all<<<dim3(64, 10), 256, 0, stream>>>(ca, ws, flag);

    bf16 *bvl = Pb[14], *vls = Pb[15], *vlb = Pb[16],
         *W1 = Pb[17], *W2 = Pb[19], *b2v = Pb[20],
         *Wp = Pb[21], *bp = Pb[22], *ps = Pb[23], *pb = Pb[24];

    k_xt<<<dim3(25, 12, 8), 256, 0, stream>>>(d_in[0], xt, flag);
    k_abfull<<<dim3(392), 256, 0, stream>>>(mb, idxs, abfull);

    k_proj_m<<<dim3(7, 12, 8), 256, 0, stream>>>(xt, wqkv, alf, bef, qbuf, kbuf, vbuf);
    k_vt<<<dim3(25, 32, 8), 256, 0, stream>>>(vbuf, vt);

    for (int bi0 = 0; bi0 < Bn; bi0 += GB) {
        k_attA<<<dim3(98, GB), 256, 0, stream>>>(qbuf, kbuf, abfull, W1, attn, sums, bi0);
        k_attB<<<dim3(25, 4, GB), 256, 0, stream>>>(attn, sums, vt, W2, b2v, obuf, bi0);
    }

    k_dwconv_add<<<dim3(1, Nn / 2, 8), 256, 0, stream>>>(vbuf, wvlt, bvl, vls, vlb, obuf);
    k_outproj_m<<<dim3(7, 6, 8), 256, 0, stream>>>(Wp, obuf, bp, ps, pb, d_out, flag);
}

// Round 11
// 254.055 us; speedup vs baseline: 1.6089x; 1.6089x over previous
//
#include <hip/hip_runtime.h>
#include <hip/hip_bf16.h>

typedef __hip_bfloat16 bf16;
typedef __attribute__((ext_vector_type(8))) short short8v;
typedef __attribute__((ext_vector_type(4))) short short4v;
typedef __attribute__((ext_vector_type(4))) float f32x4;
typedef __attribute__((ext_vector_type(2))) float f32x2;

__device__ __forceinline__ float b2f(bf16 v){ return __bfloat162float(v); }
__device__ __forceinline__ bf16  f2b(float v){ return __float2bfloat16(v); }
__device__ __forceinline__ float su2f(short s){
    unsigned short us = (unsigned short)s;
    return __bfloat162float(*reinterpret_cast<bf16*>(&us));
}
__device__ __forceinline__ float ldf(const void* t, size_t i, int isb){
    return isb ? b2f(((const bf16*)t)[i]) : ((const float*)t)[i];
}

constexpr int Bn = 8, CIN = 384, RESn = 28, Nn = 784, DHn = 1024;
constexpr int AST = 800;   // padded attn/vt K-stride (25*32)

// ---------------------------------------------------- async global->LDS 16B
__device__ __forceinline__ void gload16(const void* g, void* l)
{
    __builtin_amdgcn_global_load_lds(
        (const __attribute__((address_space(1))) void*)g,
        (__attribute__((address_space(3))) void*)l, 16, 0, 0);
}

// -------------------------------------------------- dtype detector (1 thread)
__global__ void k_detect(const unsigned* __restrict__ xw, int* __restrict__ flag)
{
    if (blockIdx.x == 0 && threadIdx.x == 0) {
        int cnt = 0;
        for (int i = 0; i < 256; ++i) {
            unsigned lo = xw[i] & 0xFFFFu;
            int e = (int)((lo >> 7) & 0xFF);
            if (e >= 112 && e <= 132) ++cnt;
        }
        *flag = (cnt >= 128) ? 1 : 0;
    }
}

// -- fused prep: wpack | affine | mixbias | dw-weight transpose (reads d_in raw)
struct PtrArgs { const void* p[26]; };
__global__ __launch_bounds__(256) void k_prep(PtrArgs a, bf16* __restrict__ Wqkv,
                                              float* __restrict__ al, float* __restrict__ be,
                                              float* __restrict__ mb, bf16* __restrict__ Wvlt,
                                              const int* __restrict__ flag)
{
    const int isb = *flag;
    const int tid = threadIdx.x;
    const int role = blockIdx.y;
    if (role == 0) {
        int stride = gridDim.x * 256;
        for (int e = blockIdx.x * 256 + tid; e < 1536 * 384; e += stride) {
            int co = e / 384, k = e % 384;
            const void* src; int lc;
            if (co < 256)      { src = a.p[1]; lc = co; }
            else if (co < 512) { src = a.p[5]; lc = co - 256; }
            else               { src = a.p[9]; lc = co - 512; }
            Wqkv[e] = f2b(ldf(src, (size_t)lc * 384 + k, isb));
        }
    } else if (role == 1) {
        int co = blockIdx.x * 256 + tid;
        if (co < 1536) {
            const void *b_, *s_, *h_; int lc;
            if (co < 256)      { b_ = a.p[2];  s_ = a.p[3];  h_ = a.p[4];  lc = co; }
            else if (co < 512) { b_ = a.p[6];  s_ = a.p[7];  h_ = a.p[8];  lc = co - 256; }
            else               { b_ = a.p[10]; s_ = a.p[11]; h_ = a.p[12]; lc = co - 512; }
            float aa = ldf(s_, lc, isb);
            al[co] = aa;
            be[co] = ldf(b_, lc, isb) * aa + ldf(h_, lc, isb);
        }
    } else if (role == 2) {
        int i = blockIdx.x * 256 + tid;
        if (i < 8 * Nn) {
            int g = i / Nn, p = i % Nn;
            float acc = ldf(a.p[18], g, isb);
            #pragma unroll
            for (int h = 0; h < 8; ++h)
                acc += ldf(a.p[17], g * 8 + h, isb) * ldf(a.p[25], (size_t)h * Nn + p, isb);
            mb[i] = acc;
        }
    } else {
        int e = blockIdx.x * 256 + tid;   // Wvl [1024][9] -> Wvlt [9][1024]
        if (e < 1024 * 9) {
            int c = e / 9, tap = e % 9;
            Wvlt[tap * 1024 + c] = f2b(ldf(a.p[13], e, isb));
        }
    }
}

// ------------------------------------- convert needed tensors -> bf16
struct ConvArgs { const void* src[10]; unsigned long long dstoff[10]; int n[10]; };
__global__ void k_convb_all(ConvArgs a, char* __restrict__ ws, const int* __restrict__ flag)
{
    int i = blockIdx.y;
    int n = a.n[i];
    const void* s = a.src[i];
    bf16* d = (bf16*)(ws + a.dstoff[i]);
    int isb = *flag;
    int stride = gridDim.x * blockDim.x;
    for (int t = blockIdx.x * blockDim.x + threadIdx.x; t < n; t += stride)
        d[t] = isb ? ((const bf16*)s)[t] : f2b(((const float*)s)[t]);
}

// ------------------- expand mb through idx: abfull[g][n][m] (b-independent)
__global__ __launch_bounds__(256) void k_abfull(
    const float* __restrict__ mb, const int* __restrict__ idxs,
    bf16* __restrict__ abfull)
{
    __shared__ float mbs[8][Nn];
    const int tid = threadIdx.x;
    for (int i = tid; i < 8 * Nn; i += 256) ((float*)mbs)[i] = mb[i];
    __syncthreads();
    const int nstart = blockIdx.x * 2;
    for (int n = nstart; n < nstart + 2; ++n) {
        for (int m = tid; m < Nn; m += 256) {
            int id = idxs[(size_t)n * Nn + m];
            #pragma unroll
            for (int g = 0; g < 8; ++g)
                abfull[((size_t)g * Nn + n) * AST + m] = f2b(mbs[g][id]);
        }
    }
}

// ------------- x transpose + inline convert: [b][384][784] -> [b][784][384]
__global__ __launch_bounds__(256) void k_xt(const void* __restrict__ xr, bf16* __restrict__ xt,
                                            const int* __restrict__ flag)
{
    const int isb = *flag;
    __shared__ bf16 t[32][33];
    int b = blockIdx.z, n0 = blockIdx.x * 32, c0 = blockIdx.y * 32;
    int tid = threadIdx.x;
    for (int i = tid; i < 1024; i += 256) {
        int r = i >> 5, c = i & 31;
        int n = n0 + c;
        t[r][c] = (n < Nn) ? f2b(ldf(xr, ((size_t)b * CIN + c0 + r) * Nn + n, isb)) : f2b(0.f);
    }
    __syncthreads();
    for (int i = tid; i < 1024; i += 256) {
        int r = i >> 5, c = i & 31;
        int n = n0 + r;
        if (n < Nn) xt[((size_t)b * Nn + n) * CIN + c0 + c] = t[c][r];
    }
}

// --------------------- v transpose: [n][c] -> [c][n] (stride AST, zero-padded)
__global__ __launch_bounds__(256) void k_vt(const bf16* __restrict__ vbuf, bf16* __restrict__ vt)
{
    __shared__ bf16 t[32][33];
    int b = blockIdx.z, n0 = blockIdx.x * 32, c0 = blockIdx.y * 32;
    int tid = threadIdx.x;
    for (int i = tid; i < 1024; i += 256) {
        int r = i >> 5, c = i & 31;
        int n = n0 + r;
        t[r][c] = (n < Nn) ? vbuf[((size_t)b * Nn + n) * DHn + c0 + c] : f2b(0.f);
    }
    __syncthreads();
    for (int i = tid; i < 1024; i += 256) {
        int r = i >> 5, c = i & 31;
        int n = n0 + c;   // n < 800 always (25*32 grid)
        vt[((size_t)b * DHn + c0 + r) * AST + n] = t[c][r];
    }
}

// ------------------- generic MFMA core: tile (MI*32) x 128, BK=32, gload_lds
template<int MI>
__device__ __forceinline__ void gemm_core(
    const bf16* __restrict__ A, int lda, int rowsA, int arow0,
    const bf16* __restrict__ B, int ldb, int rowsB, int brow0,
    int K, short* ldsA, short* ldsB, f32x4 (&acc)[MI][4])
{
    const int tid  = threadIdx.x;
    const int lane = tid & 63;
    const int wm   = tid >> 7, wn = (tid >> 6) & 1;
    const int rsub = ((tid >> 6) << 4) | (tid & 15);
    const int q    = (tid >> 4) & 3;
    const int wbase = tid & 192;
    const short8v* A8 = (const short8v*)ldsA;
    const short8v* B8 = (const short8v*)ldsB;

    for (int k0 = 0; k0 < K; k0 += 32) {
        __syncthreads();
        #pragma unroll
        for (int c = 0; c < MI / 2; ++c) {
            int row = arow0 + c * 64 + rsub; row = row < rowsA ? row : rowsA - 1;
            gload16((const short*)A + (size_t)row * lda + k0 + q * 8,
                    ldsA + (size_t)(c * 256 + wbase) * 8);
        }
        #pragma unroll
        for (int c = 0; c < 2; ++c) {
            int row = brow0 + c * 64 + rsub; row = row < rowsB ? row : rowsB - 1;
            gload16((const short*)B + (size_t)row * ldb + k0 + q * 8,
                    ldsB + (size_t)(c * 256 + wbase) * 8);
        }
        __syncthreads();
        short8v a[MI], bb[4];
        #pragma unroll
        for (int i = 0; i < MI; ++i) a[i] = A8[(wm * MI + i) * 64 + lane];
        #pragma unroll
        for (int j = 0; j < 4; ++j) bb[j] = B8[(wn * 4 + j) * 64 + lane];
        #pragma unroll
        for (int i = 0; i < MI; ++i)
            #pragma unroll
            for (int j = 0; j < 4; ++j)
                acc[i][j] = __builtin_amdgcn_mfma_f32_16x16x32_bf16(a[i], bb[j], acc[i][j], 0, 0, 0);
    }
}

#define EPI_COORDS(MI)                                      \
    const int tid  = threadIdx.x;                           \
    const int lane = tid & 63;                              \
    const int wm   = tid >> 7, wn = (tid >> 6) & 1;         \
    const int rq   = lane >> 4, cl = lane & 15; (void)rq;

// --------------------------------------------- q/k/v projection + BN (MFMA)
__global__ __launch_bounds__(256) void k_proj_m(
    const bf16* __restrict__ xt, const bf16* __restrict__ Wqkv,
    const float* __restrict__ al, const float* __restrict__ be,
    bf16* __restrict__ qbuf, bf16* __restrict__ kbuf, bf16* __restrict__ vbuf)
{
    __shared__ short ldsA[4096], ldsB[4096];
    const int n0 = blockIdx.x * 128, co0 = blockIdx.y * 128;
    const int b = blockIdx.z;
    f32x4 acc[4][4] = {};
    gemm_core<4>(xt + (size_t)b * Nn * CIN, CIN, Nn, n0,
                 Wqkv, CIN, 1536, co0, CIN, ldsA, ldsB, acc);
    EPI_COORDS(4)
    #pragma unroll
    for (int i = 0; i < 4; ++i)
        #pragma unroll
        for (int j = 0; j < 4; ++j) {
            int co = co0 + (wn * 4 + j) * 16 + cl;
            float a_ = al[co], bb_ = be[co];
            int nb = n0 + (wm * 4 + i) * 16 + rq * 4;
            #pragma unroll
            for (int r = 0; r < 4; ++r) {
                int n = nb + r;
                if (n >= Nn) continue;
                float y = a_ * acc[i][j][r] + bb_;
                if (co < 256)      qbuf[((size_t)b * Nn + n) * 256 + co]       = f2b(y);
                else if (co < 512) kbuf[((size_t)b * Nn + n) * 256 + (co-256)] = f2b(y);
                else               vbuf[((size_t)b * Nn + n) * DHn + (co-512)] = f2b(y);
            }
        }
}

// ----------------------- raw per-head logits: qk[h][n][m], K=32 (no mix/bias)
__global__ __launch_bounds__(256) void k_logits_raw(
    const bf16* __restrict__ qbuf, const bf16* __restrict__ kbuf,
    bf16* __restrict__ attn, int bi0)
{
    __shared__ short ldsA[4096], ldsB[4096];
    const int n0 = blockIdx.x * 128, m0 = blockIdx.y * 128;
    const int z = blockIdx.z, h = z & 7, bloc = z >> 3, b = bi0 + bloc;
    f32x4 acc[4][4] = {};
    gemm_core<4>(qbuf + (size_t)b * Nn * 256 + h * 32, 256, Nn, n0,
                 kbuf + (size_t)b * Nn * 256 + h * 32, 256, Nn, m0,
                 32, ldsA, ldsB, acc);
    bf16* arow = attn + (size_t)(bloc * 8 + h) * Nn * AST;
    EPI_COORDS(4)
    #pragma unroll
    for (int i = 0; i < 4; ++i)
        #pragma unroll
        for (int j = 0; j < 4; ++j) {
            int m = m0 + (wn * 4 + j) * 16 + cl;
            if (m >= Nn) continue;
            int nb = n0 + (wm * 4 + i) * 16 + rq * 4;
            #pragma unroll
            for (int r = 0; r < 4; ++r) {
                int n = nb + r;
                if (n < Nn) arow[(size_t)n * AST + m] = f2b(acc[i][j][r]);
            }
        }
}

// --- fused: th1 mix (+abfull) + softmax (no-max, clamp) + th2 mix, registers
__global__ __launch_bounds__(256) void k_softmax_mix(
    bf16* __restrict__ attn_all, const bf16* __restrict__ abfull,
    const bf16* __restrict__ W1, const bf16* __restrict__ W2, const bf16* __restrict__ b2v)
{
    const int n = blockIdx.x, bloc = blockIdx.y;
    const int tid = threadIdx.x;
    bf16* base = attn_all + (size_t)bloc * 8 * Nn * AST;
    __shared__ float w1s[64], w2s[64], b2sh[8], lis[8], wred[4][8];
    if (tid < 64) { w1s[tid] = b2f(W1[tid]) * 0.17677669529663687f; w2s[tid] = b2f(W2[tid]); }
    if (tid < 8)  b2sh[tid] = b2f(b2v[tid]);
    __syncthreads();

    const bool live = tid < 196;
    const int m0 = (live ? tid : 195) * 4;

    f32x2 raw2[8][2];
    #pragma unroll
    for (int h = 0; h < 8; ++h) {
        short4v v = *(const short4v*)(base + ((size_t)h * Nn + n) * AST + m0);
        raw2[h][0] = f32x2{su2f(v[0]), su2f(v[1])};
        raw2[h][1] = f32x2{su2f(v[2]), su2f(v[3])};
    }

    float out[8][4];
    #pragma unroll
    for (int g = 0; g < 8; ++g) {
        short4v bv = *(const short4v*)(abfull + ((size_t)g * Nn + n) * AST + m0);
        f32x2 a0 = {su2f(bv[0]), su2f(bv[1])};
        f32x2 a1 = {su2f(bv[2]), su2f(bv[3])};
        #pragma unroll
        for (int h = 0; h < 8; ++h) {
            float w = w1s[g * 8 + h];
            f32x2 wv = {w, w};
            a0 += raw2[h][0] * wv;
            a1 += raw2[h][1] * wv;
        }
        out[g][0] = __expf(fminf(a0[0], 60.f));
        out[g][1] = __expf(fminf(a0[1], 60.f));
        out[g][2] = __expf(fminf(a1[0], 60.f));
        out[g][3] = __expf(fminf(a1[1], 60.f));
        float s = live ? (out[g][0] + out[g][1]) + (out[g][2] + out[g][3]) : 0.f;
        #pragma unroll
        for (int sh = 32; sh > 0; sh >>= 1) s += __shfl_xor(s, sh, 64);
        if ((tid & 63) == 0) wred[tid >> 6][g] = s;
    }
    __syncthreads();
    if (tid < 8)
        lis[tid] = 1.f / (wred[0][tid] + wred[1][tid] + wred[2][tid] + wred[3][tid]);
    __syncthreads();

    f32x2 p2[8][2];
    #pragma unroll
    for (int h = 0; h < 8; ++h) {
        float lh = lis[h];
        p2[h][0] = f32x2{out[h][0] * lh, out[h][1] * lh};
        p2[h][1] = f32x2{out[h][2] * lh, out[h][3] * lh};
    }
    if (live) {
        #pragma unroll
        for (int g = 0; g < 8; ++g) {
            f32x2 acc0 = {b2sh[g], b2sh[g]};
            f32x2 acc1 = acc0;
            #pragma unroll
            for (int h = 0; h < 8; ++h) {
                float w = w2s[g * 8 + h];
                f32x2 wv = {w, w};
                acc0 += p2[h][0] * wv;
                acc1 += p2[h][1] * wv;
            }
            short4v sv;
            bf16 b0 = f2b(acc0[0]); sv[0] = *reinterpret_cast<short*>(&b0);
            bf16 b1 = f2b(acc0[1]); sv[1] = *reinterpret_cast<short*>(&b1);
            bf16 b2 = f2b(acc1[0]); sv[2] = *reinterpret_cast<short*>(&b2);
            bf16 b3 = f2b(acc1[1]); sv[3] = *reinterpret_cast<short*>(&b3);
            *(short4v*)(base + ((size_t)g * Nn + n) * AST + m0) = sv;
        }
    }
}

// ------------------------------------------------ PV: obuf[b][n][c] = P2 · v
__global__ __launch_bounds__(256) void k_pv_m(
    const bf16* __restrict__ attn, const bf16* __restrict__ vt,
    bf16* __restrict__ obuf, int bi0)
{
    __shared__ short ldsA[2048], ldsB[4096];
    const int n0 = blockIdx.x * 64;
    const int z = blockIdx.z, g = z & 7, bloc = z >> 3, b = bi0 + bloc;
    f32x4 acc[2][4] = {};
    gemm_core<2>(attn + (size_t)(bloc * 8 + g) * Nn * AST, AST, Nn, n0,
                 vt + ((size_t)b * DHn + g * 128) * AST, AST, 128, 0,
                 AST, ldsA, ldsB, acc);
    bf16* ob = obuf + (size_t)b * Nn * DHn + g * 128;
    EPI_COORDS(2)
    #pragma unroll
    for (int i = 0; i < 2; ++i)
        #pragma unroll
        for (int j = 0; j < 4; ++j) {
            int d = (wn * 4 + j) * 16 + cl;
            int nb = n0 + (wm * 2 + i) * 16 + rq * 4;
            #pragma unroll
            for (int r = 0; r < 4; ++r) {
                int n = nb + r;
                if (n < Nn) ob[(size_t)n * DHn + d] = f2b(acc[i][j][r]);
            }
        }
}

// ---- depthwise conv+BN, ADDS into obuf (o += vl), fully vectorized weights
__global__ __launch_bounds__(256) void k_dwconv_add(
    const bf16* __restrict__ vbuf, const bf16* __restrict__ Wvlt,
    const bf16* __restrict__ bvl, const bf16* __restrict__ vls, const bf16* __restrict__ vlb,
    bf16* __restrict__ obuf)
{
    const int t = threadIdx.x;
    const int n = blockIdx.y * 2 + (t >> 7);
    const int bi = blockIdx.z;
    const int c0 = (t & 127) * 8;
    const int h = n / RESn, w = n % RESn;
    float acc[8] = {};
    #pragma unroll
    for (int dh = -1; dh <= 1; ++dh)
        #pragma unroll
        for (int dw = -1; dw <= 1; ++dw) {
            int hh = h + dh, ww = w + dw;
            if (hh < 0 || hh >= RESn || ww < 0 || ww >= RESn) continue;
            int widx = (dh + 1) * 3 + (dw + 1);
            short8v wv = *(const short8v*)&Wvlt[widx * 1024 + c0];
            short8v v  = *(const short8v*)&vbuf[((size_t)bi * Nn + hh * RESn + ww) * DHn + c0];
            #pragma unroll
            for (int u = 0; u < 8; ++u)
                acc[u] += su2f(wv[u]) * su2f(v[u]);
        }
    short8v bv = *(const short8v*)&bvl[c0];
    short8v sv = *(const short8v*)&vls[c0];
    short8v hv = *(const short8v*)&vlb[c0];
    size_t off = ((size_t)bi * Nn + n) * DHn + c0;
    short8v ov = *(short8v*)&obuf[off];
    short8v res;
    #pragma unroll
    for (int u = 0; u < 8; ++u) {
        float vl = su2f(sv[u]) * (acc[u] + su2f(bv[u])) + su2f(hv[u]);
        bf16 bo = f2b(su2f(ov[u]) + vl);
        res[u] = *reinterpret_cast<short*>(&bo);
    }
    *(short8v*)&obuf[off] = res;
}

// --------------------------------------------- output projection + BN (MFMA)
__global__ __launch_bounds__(256) void k_outproj_m(
    const bf16* __restrict__ Wp, const bf16* __restrict__ obuf,
    const bf16* __restrict__ bp, const bf16* __restrict__ ps, const bf16* __restrict__ pb,
    void* __restrict__ outv, const int* __restrict__ flag)
{
    __shared__ short ldsA[2048], ldsB[4096];
    const int n0 = blockIdx.x * 128, oc0 = blockIdx.y * 64;
    const int b = blockIdx.z;
    f32x4 acc[2][4] = {};
    gemm_core<2>(Wp, DHn, 384, oc0,
                 obuf + (size_t)b * Nn * DHn, DHn, Nn, n0,
                 DHn, ldsA, ldsB, acc);
    const int isb = *flag;
    EPI_COORDS(2)
    #pragma unroll
    for (int i = 0; i < 2; ++i)
        #pragma unroll
        for (int j = 0; j < 4; ++j) {
            int n = n0 + (wn * 4 + j) * 16 + cl;
            if (n >= Nn) continue;
            int ocb = oc0 + (wm * 2 + i) * 16 + rq * 4;
            #pragma unroll
            for (int r = 0; r < 4; ++r) {
                int oc = ocb + r;
                float a_ = b2f(ps[oc]);
                float be_ = b2f(bp[oc]) * a_ + b2f(pb[oc]);
                float y = a_ * acc[i][j][r] + be_;
                size_t idx = ((size_t)b * CIN + oc) * Nn + n;
                if (isb) ((bf16*)outv)[idx] = f2b(y);
                else     ((float*)outv)[idx] = y;
            }
        }
}

extern "C" void kernel_launch(void* const* d_in, const int* in_sizes, int n_in,
                              void* d_out, int out_size, void* d_ws, size_t ws_size,
                              hipStream_t stream)
{
    char* ws = (char*)d_ws;
    auto align256 = [](size_t v) { return (v + 255) & ~(size_t)255; };

    size_t off = 0;
    size_t off_flag = off;            off = align256(off + 4);
    size_t p_off[26];
    for (int i = 0; i < 26; ++i) { p_off[i] = off; off = align256(off + (size_t)in_sizes[i] * 2); }
    size_t off_mb   = off; off = align256(off + (size_t)8 * Nn * 4);
    size_t off_ab   = off; off = align256(off + (size_t)8 * Nn * AST * 2);
    size_t off_q    = off; off = align256(off + (size_t)Bn * Nn * 256 * 2);
    size_t off_k    = off; off = align256(off + (size_t)Bn * Nn * 256 * 2);
    size_t off_v    = off; off = align256(off + (size_t)Bn * Nn * DHn * 2);
    size_t off_vt   = off; off = align256(off + (size_t)Bn * DHn * AST * 2);
    size_t off_o    = off; off = align256(off + (size_t)Bn * Nn * DHn * 2);
    size_t off_xt   = off; off = align256(off + (size_t)Bn * Nn * CIN * 2);
    size_t off_wqkv = off; off = align256(off + (size_t)1536 * CIN * 2);
    size_t off_al   = off; off = align256(off + (size_t)1536 * 4);
    size_t off_be   = off; off = align256(off + (size_t)1536 * 4);
    size_t off_wvlt = off; off = align256(off + (size_t)9 * 1024 * 2);
    size_t base = off;

    // GB=4 preferred: 4-batch attn tile (40 MB) stays L3-resident across the
    // logits->softmax->pv chain; GB=8's 80 MB was evicted (round-9 FETCH=60MB).
    const size_t attn_per_b = (size_t)8 * Nn * AST * 2;
    int GB = 0;
    const int cand[3] = {4, 2, 1};
    for (int ci = 0; ci < 3; ++ci) {
        if (base + (size_t)cand[ci] * attn_per_b + 512 <= ws_size) { GB = cand[ci]; break; }
    }
    if (!GB) return; // ws too small -> zeros out (diagnostic absmax ~17.4)

    size_t off_attn = base;

    int*  flag = (int*)(ws + off_flag);
    bf16* Pb[26];
    for (int i = 0; i < 26; ++i) Pb[i] = (bf16*)(ws + p_off[i]);
    float* mb    = (float*)(ws + off_mb);
    bf16* abfull = (bf16*)(ws + off_ab);
    bf16* qbuf  = (bf16*)(ws + off_q);
    bf16* kbuf  = (bf16*)(ws + off_k);
    bf16* vbuf  = (bf16*)(ws + off_v);
    bf16* vt    = (bf16*)(ws + off_vt);
    bf16* obuf  = (bf16*)(ws + off_o);
    bf16* xt    = (bf16*)(ws + off_xt);
    bf16* wqkv  = (bf16*)(ws + off_wqkv);
    float* alf  = (float*)(ws + off_al);
    float* bef  = (float*)(ws + off_be);
    bf16* wvlt  = (bf16*)(ws + off_wvlt);
    bf16* attn  = (bf16*)(ws + off_attn);
    const int* idxs = (const int*)d_in[26];

    k_detect<<<1, 64, 0, stream>>>((const unsigned*)d_in[0], flag);

    PtrArgs pa;
    for (int i = 0; i < 26; ++i) pa.p[i] = d_in[i];
    k_prep<<<dim3(288, 4), 256, 0, stream>>>(pa, wqkv, alf, bef, mb, wvlt, flag);

    const int cidx[10] = {14, 15, 16, 17, 19, 20, 21, 22, 23, 24};
    ConvArgs ca;
    for (int i = 0; i < 10; ++i) {
        ca.src[i] = d_in[cidx[i]];
        ca.dstoff[i] = p_off[cidx[i]];
        ca.n[i] = in_sizes[cidx[i]];
    }
    k_convb_all<<<dim3(64, 10), 256, 0, stream>>>(ca, ws, flag);

    bf16 *bvl = Pb[14], *vls = Pb[15], *vlb = Pb[16],
         *W1 = Pb[17], *W2 = Pb[19], *b2v = Pb[20],
         *Wp = Pb[21], *bp = Pb[22], *ps = Pb[23], *pb = Pb[24];

    k_xt<<<dim3(25, 12, 8), 256, 0, stream>>>(d_in[0], xt, flag);
    k_abfull<<<dim3(392), 256, 0, stream>>>(mb, idxs, abfull);

    k_proj_m<<<dim3(7, 12, 8), 256, 0, stream>>>(xt, wqkv, alf, bef, qbuf, kbuf, vbuf);
    k_vt<<<dim3(25, 32, 8), 256, 0, stream>>>(vbuf, vt);

    for (int bi0 = 0; bi0 < Bn; bi0 += GB) {
        k_logits_raw<<<dim3(7, 7, GB * 8), 256, 0, stream>>>(qbuf, kbuf, attn, bi0);
        k_softmax_mix<<<dim3(Nn, GB), 256, 0, stream>>>(attn, abfull, W1, W2, b2v);
        k_pv_m<<<dim3(13, 1, GB * 8), 256, 0, stream>>>(attn, vt, obuf, bi0);
    }

    k_dwconv_add<<<dim3(1, Nn / 2, 8), 256, 0, stream>>>(vbuf, wvlt, bvl, vls, vlb, obuf);
    k_outproj_m<<<dim3(7, 6, 8), 256, 0, stream>>>(Wp, obuf, bp, ps, pb, d_out, flag);
}

// Round 12
// 240.448 us; speedup vs baseline: 1.6999x; 1.0566x over previous
//
#include <hip/hip_runtime.h>
#include <hip/hip_bf16.h>

typedef __hip_bfloat16 bf16;
typedef __attribute__((ext_vector_type(8))) short short8v;
typedef __attribute__((ext_vector_type(4))) short short4v;
typedef __attribute__((ext_vector_type(4))) float f32x4;
typedef __attribute__((ext_vector_type(2))) float f32x2;

__device__ __forceinline__ float b2f(bf16 v){ return __bfloat162float(v); }
__device__ __forceinline__ bf16  f2b(float v){ return __float2bfloat16(v); }
__device__ __forceinline__ float su2f(short s){
    unsigned short us = (unsigned short)s;
    return __bfloat162float(*reinterpret_cast<bf16*>(&us));
}
__device__ __forceinline__ float ldf(const void* t, size_t i, int isb){
    return isb ? b2f(((const bf16*)t)[i]) : ((const float*)t)[i];
}

constexpr int Bn = 8, CIN = 384, RESn = 28, Nn = 784, DHn = 1024;
constexpr int AST = 800;   // padded attn/vt K-stride (25*32)

// ---------------------------------------------------- async global->LDS 16B
__device__ __forceinline__ void gload16(const void* g, void* l)
{
    __builtin_amdgcn_global_load_lds(
        (const __attribute__((address_space(1))) void*)g,
        (__attribute__((address_space(3))) void*)l, 16, 0, 0);
}

// -------------------------------------------------- dtype detector (1 thread)
__global__ void k_detect(const unsigned* __restrict__ xw, int* __restrict__ flag)
{
    if (blockIdx.x == 0 && threadIdx.x == 0) {
        int cnt = 0;
        for (int i = 0; i < 256; ++i) {
            unsigned lo = xw[i] & 0xFFFFu;
            int e = (int)((lo >> 7) & 0xFF);
            if (e >= 112 && e <= 132) ++cnt;
        }
        *flag = (cnt >= 128) ? 1 : 0;
    }
}

// -- fused prep: wpack | affine | mixbias | dw-weight transpose (reads d_in raw)
struct PtrArgs { const void* p[26]; };
__global__ __launch_bounds__(256) void k_prep(PtrArgs a, bf16* __restrict__ Wqkv,
                                              float* __restrict__ al, float* __restrict__ be,
                                              float* __restrict__ mb, bf16* __restrict__ Wvlt,
                                              const int* __restrict__ flag)
{
    const int isb = *flag;
    const int tid = threadIdx.x;
    const int role = blockIdx.y;
    if (role == 0) {
        int stride = gridDim.x * 256;
        for (int e = blockIdx.x * 256 + tid; e < 1536 * 384; e += stride) {
            int co = e / 384, k = e % 384;
            const void* src; int lc;
            if (co < 256)      { src = a.p[1]; lc = co; }
            else if (co < 512) { src = a.p[5]; lc = co - 256; }
            else               { src = a.p[9]; lc = co - 512; }
            Wqkv[e] = f2b(ldf(src, (size_t)lc * 384 + k, isb));
        }
    } else if (role == 1) {
        int co = blockIdx.x * 256 + tid;
        if (co < 1536) {
            const void *b_, *s_, *h_; int lc;
            if (co < 256)      { b_ = a.p[2];  s_ = a.p[3];  h_ = a.p[4];  lc = co; }
            else if (co < 512) { b_ = a.p[6];  s_ = a.p[7];  h_ = a.p[8];  lc = co - 256; }
            else               { b_ = a.p[10]; s_ = a.p[11]; h_ = a.p[12]; lc = co - 512; }
            float aa = ldf(s_, lc, isb);
            al[co] = aa;
            be[co] = ldf(b_, lc, isb) * aa + ldf(h_, lc, isb);
        }
    } else if (role == 2) {
        int i = blockIdx.x * 256 + tid;
        if (i < 8 * Nn) {
            int g = i / Nn, p = i % Nn;
            float acc = ldf(a.p[18], g, isb);
            #pragma unroll
            for (int h = 0; h < 8; ++h)
                acc += ldf(a.p[17], g * 8 + h, isb) * ldf(a.p[25], (size_t)h * Nn + p, isb);
            mb[i] = acc;
        }
    } else {
        int e = blockIdx.x * 256 + tid;   // Wvl [1024][9] -> Wvlt [9][1024]
        if (e < 1024 * 9) {
            int c = e / 9, tap = e % 9;
            Wvlt[tap * 1024 + c] = f2b(ldf(a.p[13], e, isb));
        }
    }
}

// ------------------------------------- convert needed tensors -> bf16
struct ConvArgs { const void* src[10]; unsigned long long dstoff[10]; int n[10]; };
__global__ void k_convb_all(ConvArgs a, char* __restrict__ ws, const int* __restrict__ flag)
{
    int i = blockIdx.y;
    int n = a.n[i];
    const void* s = a.src[i];
    bf16* d = (bf16*)(ws + a.dstoff[i]);
    int isb = *flag;
    int stride = gridDim.x * blockDim.x;
    for (int t = blockIdx.x * blockDim.x + threadIdx.x; t < n; t += stride)
        d[t] = isb ? ((const bf16*)s)[t] : f2b(((const float*)s)[t]);
}

// ------------------- expand mb through idx: abfull[g][n][m] (b-independent)
__global__ __launch_bounds__(256) void k_abfull(
    const float* __restrict__ mb, const int* __restrict__ idxs,
    bf16* __restrict__ abfull)
{
    __shared__ float mbs[8][Nn];
    const int tid = threadIdx.x;
    for (int i = tid; i < 8 * Nn; i += 256) ((float*)mbs)[i] = mb[i];
    __syncthreads();
    const int nstart = blockIdx.x * 2;
    for (int n = nstart; n < nstart + 2; ++n) {
        for (int m = tid; m < Nn; m += 256) {
            int id = idxs[(size_t)n * Nn + m];
            #pragma unroll
            for (int g = 0; g < 8; ++g)
                abfull[((size_t)g * Nn + n) * AST + m] = f2b(mbs[g][id]);
        }
    }
}

// ------------- x transpose + inline convert: [b][384][784] -> [b][784][384]
__global__ __launch_bounds__(256) void k_xt(const void* __restrict__ xr, bf16* __restrict__ xt,
                                            const int* __restrict__ flag)
{
    const int isb = *flag;
    __shared__ bf16 t[32][33];
    int b = blockIdx.z, n0 = blockIdx.x * 32, c0 = blockIdx.y * 32;
    int tid = threadIdx.x;
    for (int i = tid; i < 1024; i += 256) {
        int r = i >> 5, c = i & 31;
        int n = n0 + c;
        t[r][c] = (n < Nn) ? f2b(ldf(xr, ((size_t)b * CIN + c0 + r) * Nn + n, isb)) : f2b(0.f);
    }
    __syncthreads();
    for (int i = tid; i < 1024; i += 256) {
        int r = i >> 5, c = i & 31;
        int n = n0 + r;
        if (n < Nn) xt[((size_t)b * Nn + n) * CIN + c0 + c] = t[c][r];
    }
}

// --------------------- v transpose: [n][c] -> [c][n] (stride AST, zero-padded)
__global__ __launch_bounds__(256) void k_vt(const bf16* __restrict__ vbuf, bf16* __restrict__ vt)
{
    __shared__ bf16 t[32][33];
    int b = blockIdx.z, n0 = blockIdx.x * 32, c0 = blockIdx.y * 32;
    int tid = threadIdx.x;
    for (int i = tid; i < 1024; i += 256) {
        int r = i >> 5, c = i & 31;
        int n = n0 + r;
        t[r][c] = (n < Nn) ? vbuf[((size_t)b * Nn + n) * DHn + c0 + c] : f2b(0.f);
    }
    __syncthreads();
    for (int i = tid; i < 1024; i += 256) {
        int r = i >> 5, c = i & 31;
        int n = n0 + c;   // n < 800 always (25*32 grid)
        vt[((size_t)b * DHn + c0 + r) * AST + n] = t[c][r];
    }
}

// ------------------- generic MFMA core: tile (MI*32) x 128, BK=32, gload_lds
template<int MI>
__device__ __forceinline__ void gemm_core(
    const bf16* __restrict__ A, int lda, int rowsA, int arow0,
    const bf16* __restrict__ B, int ldb, int rowsB, int brow0,
    int K, short* ldsA, short* ldsB, f32x4 (&acc)[MI][4])
{
    const int tid  = threadIdx.x;
    const int lane = tid & 63;
    const int wm   = tid >> 7, wn = (tid >> 6) & 1;
    const int rsub = ((tid >> 6) << 4) | (tid & 15);
    const int q    = (tid >> 4) & 3;
    const int wbase = tid & 192;
    const short8v* A8 = (const short8v*)ldsA;
    const short8v* B8 = (const short8v*)ldsB;

    for (int k0 = 0; k0 < K; k0 += 32) {
        __syncthreads();
        #pragma unroll
        for (int c = 0; c < MI / 2; ++c) {
            int row = arow0 + c * 64 + rsub; row = row < rowsA ? row : rowsA - 1;
            gload16((const short*)A + (size_t)row * lda + k0 + q * 8,
                    ldsA + (size_t)(c * 256 + wbase) * 8);
        }
        #pragma unroll
        for (int c = 0; c < 2; ++c) {
            int row = brow0 + c * 64 + rsub; row = row < rowsB ? row : rowsB - 1;
            gload16((const short*)B + (size_t)row * ldb + k0 + q * 8,
                    ldsB + (size_t)(c * 256 + wbase) * 8);
        }
        __syncthreads();
        short8v a[MI], bb[4];
        #pragma unroll
        for (int i = 0; i < MI; ++i) a[i] = A8[(wm * MI + i) * 64 + lane];
        #pragma unroll
        for (int j = 0; j < 4; ++j) bb[j] = B8[(wn * 4 + j) * 64 + lane];
        #pragma unroll
        for (int i = 0; i < MI; ++i)
            #pragma unroll
            for (int j = 0; j < 4; ++j)
                acc[i][j] = __builtin_amdgcn_mfma_f32_16x16x32_bf16(a[i], bb[j], acc[i][j], 0, 0, 0);
    }
}

#define EPI_COORDS(MI)                                      \
    const int tid  = threadIdx.x;                           \
    const int lane = tid & 63;                              \
    const int wm   = tid >> 7, wn = (tid >> 6) & 1;         \
    const int rq   = lane >> 4, cl = lane & 15; (void)rq;

// --------------------------------------------- q/k/v projection + BN (MFMA)
__global__ __launch_bounds__(256) void k_proj_m(
    const bf16* __restrict__ xt, const bf16* __restrict__ Wqkv,
    const float* __restrict__ al, const float* __restrict__ be,
    bf16* __restrict__ qbuf, bf16* __restrict__ kbuf, bf16* __restrict__ vbuf)
{
    __shared__ short ldsA[4096], ldsB[4096];
    const int n0 = blockIdx.x * 128, co0 = blockIdx.y * 128;
    const int b = blockIdx.z;
    f32x4 acc[4][4] = {};
    gemm_core<4>(xt + (size_t)b * Nn * CIN, CIN, Nn, n0,
                 Wqkv, CIN, 1536, co0, CIN, ldsA, ldsB, acc);
    EPI_COORDS(4)
    #pragma unroll
    for (int i = 0; i < 4; ++i)
        #pragma unroll
        for (int j = 0; j < 4; ++j) {
            int co = co0 + (wn * 4 + j) * 16 + cl;
            float a_ = al[co], bb_ = be[co];
            int nb = n0 + (wm * 4 + i) * 16 + rq * 4;
            #pragma unroll
            for (int r = 0; r < 4; ++r) {
                int n = nb + r;
                if (n >= Nn) continue;
                float y = a_ * acc[i][j][r] + bb_;
                if (co < 256)      qbuf[((size_t)b * Nn + n) * 256 + co]       = f2b(y);
                else if (co < 512) kbuf[((size_t)b * Nn + n) * 256 + (co-256)] = f2b(y);
                else               vbuf[((size_t)b * Nn + n) * DHn + (co-512)] = f2b(y);
            }
        }
}

// ----------------------- raw per-head logits: qk[h][n][m], K=32 (no mix/bias)
__global__ __launch_bounds__(256) void k_logits_raw(
    const bf16* __restrict__ qbuf, const bf16* __restrict__ kbuf,
    bf16* __restrict__ attn, int bi0)
{
    __shared__ short ldsA[4096], ldsB[4096];
    const int n0 = blockIdx.x * 128, m0 = blockIdx.y * 128;
    const int z = blockIdx.z, h = z & 7, bloc = z >> 3, b = bi0 + bloc;
    f32x4 acc[4][4] = {};
    gemm_core<4>(qbuf + (size_t)b * Nn * 256 + h * 32, 256, Nn, n0,
                 kbuf + (size_t)b * Nn * 256 + h * 32, 256, Nn, m0,
                 32, ldsA, ldsB, acc);
    bf16* arow = attn + (size_t)(bloc * 8 + h) * Nn * AST;
    EPI_COORDS(4)
    #pragma unroll
    for (int i = 0; i < 4; ++i)
        #pragma unroll
        for (int j = 0; j < 4; ++j) {
            int m = m0 + (wn * 4 + j) * 16 + cl;
            if (m >= Nn) continue;
            int nb = n0 + (wm * 4 + i) * 16 + rq * 4;
            #pragma unroll
            for (int r = 0; r < 4; ++r) {
                int n = nb + r;
                if (n < Nn) arow[(size_t)n * AST + m] = f2b(acc[i][j][r]);
            }
        }
}

// --- fused: th1 mix (+abfull) + softmax (no-max, clamp) + th2 mix, registers
// block = 256 threads = 2 n-rows x 128 lanes; lane lt<98 owns m-chunk [8*lt, 8*lt+8)
__global__ __launch_bounds__(256) void k_softmax_mix(
    bf16* __restrict__ attn_all, const bf16* __restrict__ abfull,
    const bf16* __restrict__ W1, const bf16* __restrict__ W2, const bf16* __restrict__ b2v)
{
    const int bloc = blockIdx.y;
    const int tid = threadIdx.x;
    const int row = tid >> 7;           // 0..1
    const int lt  = tid & 127;
    const int n   = blockIdx.x * 2 + row;
    bf16* base = attn_all + (size_t)bloc * 8 * Nn * AST;
    __shared__ float w1s[64], w2s[64], b2sh[8], lis[2][8], wred[2][2][8];
    if (tid < 64) { w1s[tid] = b2f(W1[tid]) * 0.17677669529663687f; w2s[tid] = b2f(W2[tid]); }
    if (tid < 8)  b2sh[tid] = b2f(b2v[tid]);
    __syncthreads();

    const bool live = lt < 98;
    const int m0 = (live ? lt : 97) * 8;

    f32x2 raw2[8][4];
    #pragma unroll
    for (int h = 0; h < 8; ++h) {
        short8v v = *(const short8v*)(base + ((size_t)h * Nn + n) * AST + m0);
        #pragma unroll
        for (int p = 0; p < 4; ++p) raw2[h][p] = f32x2{su2f(v[2*p]), su2f(v[2*p+1])};
    }

    f32x2 out2[8][4];
    #pragma unroll
    for (int g = 0; g < 8; ++g) {
        short8v bv = *(const short8v*)(abfull + ((size_t)g * Nn + n) * AST + m0);
        f32x2 a[4];
        #pragma unroll
        for (int p = 0; p < 4; ++p) a[p] = f32x2{su2f(bv[2*p]), su2f(bv[2*p+1])};
        #pragma unroll
        for (int h = 0; h < 8; ++h) {
            float w = w1s[g * 8 + h];
            f32x2 wv = {w, w};
            #pragma unroll
            for (int p = 0; p < 4; ++p) a[p] += raw2[h][p] * wv;
        }
        float s = 0.f;
        #pragma unroll
        for (int p = 0; p < 4; ++p) {
            f32x2 e;
            e[0] = __expf(fminf(a[p][0], 60.f));
            e[1] = __expf(fminf(a[p][1], 60.f));
            out2[g][p] = e;
            s += e[0] + e[1];
        }
        if (!live) s = 0.f;
        #pragma unroll
        for (int sh = 32; sh > 0; sh >>= 1) s += __shfl_xor(s, sh, 64);
        if ((tid & 63) == 0) wred[row][(tid >> 6) & 1][g] = s;
    }
    __syncthreads();
    if (tid < 16) {
        int r = tid >> 3, g = tid & 7;
        lis[r][g] = 1.f / (wred[r][0][g] + wred[r][1][g]);
    }
    __syncthreads();

    #pragma unroll
    for (int h = 0; h < 8; ++h) {
        float lh = lis[row][h];
        f32x2 lv = {lh, lh};
        #pragma unroll
        for (int p = 0; p < 4; ++p) out2[h][p] *= lv;
    }
    if (live) {
        #pragma unroll
        for (int g = 0; g < 8; ++g) {
            f32x2 acc[4];
            #pragma unroll
            for (int p = 0; p < 4; ++p) acc[p] = f32x2{b2sh[g], b2sh[g]};
            #pragma unroll
            for (int h = 0; h < 8; ++h) {
                float w = w2s[g * 8 + h];
                f32x2 wv = {w, w};
                #pragma unroll
                for (int p = 0; p < 4; ++p) acc[p] += out2[h][p] * wv;
            }
            short8v sv;
            #pragma unroll
            for (int p = 0; p < 4; ++p) {
                bf16 b0 = f2b(acc[p][0]); sv[2*p]   = *reinterpret_cast<short*>(&b0);
                bf16 b1 = f2b(acc[p][1]); sv[2*p+1] = *reinterpret_cast<short*>(&b1);
            }
            *(short8v*)(base + ((size_t)g * Nn + n) * AST + m0) = sv;
        }
    }
}

// ------------------------------------------------ PV: obuf[b][n][c] = P2 · v
__global__ __launch_bounds__(256) void k_pv_m(
    const bf16* __restrict__ attn, const bf16* __restrict__ vt,
    bf16* __restrict__ obuf, int bi0)
{
    __shared__ short ldsA[2048], ldsB[4096];
    const int n0 = blockIdx.x * 64;
    const int z = blockIdx.z, g = z & 7, bloc = z >> 3, b = bi0 + bloc;
    f32x4 acc[2][4] = {};
    gemm_core<2>(attn + (size_t)(bloc * 8 + g) * Nn * AST, AST, Nn, n0,
                 vt + ((size_t)b * DHn + g * 128) * AST, AST, 128, 0,
                 AST, ldsA, ldsB, acc);
    bf16* ob = obuf + (size_t)b * Nn * DHn + g * 128;
    EPI_COORDS(2)
    #pragma unroll
    for (int i = 0; i < 2; ++i)
        #pragma unroll
        for (int j = 0; j < 4; ++j) {
            int d = (wn * 4 + j) * 16 + cl;
            int nb = n0 + (wm * 2 + i) * 16 + rq * 4;
            #pragma unroll
            for (int r = 0; r < 4; ++r) {
                int n = nb + r;
                if (n < Nn) ob[(size_t)n * DHn + d] = f2b(acc[i][j][r]);
            }
        }
}

// ---- depthwise conv+BN, ADDS into obuf (o += vl), fully vectorized weights
__global__ __launch_bounds__(256) void k_dwconv_add(
    const bf16* __restrict__ vbuf, const bf16* __restrict__ Wvlt,
    const bf16* __restrict__ bvl, const bf16* __restrict__ vls, const bf16* __restrict__ vlb,
    bf16* __restrict__ obuf)
{
    const int t = threadIdx.x;
    const int n = blockIdx.y * 2 + (t >> 7);
    const int bi = blockIdx.z;
    const int c0 = (t & 127) * 8;
    const int h = n / RESn, w = n % RESn;
    float acc[8] = {};
    #pragma unroll
    for (int dh = -1; dh <= 1; ++dh)
        #pragma unroll
        for (int dw = -1; dw <= 1; ++dw) {
            int hh = h + dh, ww = w + dw;
            if (hh < 0 || hh >= RESn || ww < 0 || ww >= RESn) continue;
            int widx = (dh + 1) * 3 + (dw + 1);
            short8v wv = *(const short8v*)&Wvlt[widx * 1024 + c0];
            short8v v  = *(const short8v*)&vbuf[((size_t)bi * Nn + hh * RESn + ww) * DHn + c0];
            #pragma unroll
            for (int u = 0; u < 8; ++u)
                acc[u] += su2f(wv[u]) * su2f(v[u]);
        }
    short8v bv = *(const short8v*)&bvl[c0];
    short8v sv = *(const short8v*)&vls[c0];
    short8v hv = *(const short8v*)&vlb[c0];
    size_t off = ((size_t)bi * Nn + n) * DHn + c0;
    short8v ov = *(short8v*)&obuf[off];
    short8v res;
    #pragma unroll
    for (int u = 0; u < 8; ++u) {
        float vl = su2f(sv[u]) * (acc[u] + su2f(bv[u])) + su2f(hv[u]);
        bf16 bo = f2b(su2f(ov[u]) + vl);
        res[u] = *reinterpret_cast<short*>(&bo);
    }
    *(short8v*)&obuf[off] = res;
}

// --------------------------------------------- output projection + BN (MFMA)
__global__ __launch_bounds__(256) void k_outproj_m(
    const bf16* __restrict__ Wp, const bf16* __restrict__ obuf,
    const bf16* __restrict__ bp, const bf16* __restrict__ ps, const bf16* __restrict__ pb,
    void* __restrict__ outv, const int* __restrict__ flag)
{
    __shared__ short ldsA[2048], ldsB[4096];
    const int n0 = blockIdx.x * 128, oc0 = blockIdx.y * 64;
    const int b = blockIdx.z;
    f32x4 acc[2][4] = {};
    gemm_core<2>(Wp, DHn, 384, oc0,
                 obuf + (size_t)b * Nn * DHn, DHn, Nn, n0,
                 DHn, ldsA, ldsB, acc);
    const int isb = *flag;
    EPI_COORDS(2)
    #pragma unroll
    for (int i = 0; i < 2; ++i)
        #pragma unroll
        for (int j = 0; j < 4; ++j) {
            int n = n0 + (wn * 4 + j) * 16 + cl;
            if (n >= Nn) continue;
            int ocb = oc0 + (wm * 2 + i) * 16 + rq * 4;
            #pragma unroll
            for (int r = 0; r < 4; ++r) {
                int oc = ocb + r;
                float a_ = b2f(ps[oc]);
                float be_ = b2f(bp[oc]) * a_ + b2f(pb[oc]);
                float y = a_ * acc[i][j][r] + be_;
                size_t idx = ((size_t)b * CIN + oc) * Nn + n;
                if (isb) ((bf16*)outv)[idx] = f2b(y);
                else     ((float*)outv)[idx] = y;
            }
        }
}

extern "C" void kernel_launch(void* const* d_in, const int* in_sizes, int n_in,
                              void* d_out, int out_size, void* d_ws, size_t ws_size,
                              hipStream_t stream)
{
    char* ws = (char*)d_ws;
    auto align256 = [](size_t v) { return (v + 255) & ~(size_t)255; };

    size_t off = 0;
    size_t off_flag = off;            off = align256(off + 4);
    size_t p_off[26];
    for (int i = 0; i < 26; ++i) { p_off[i] = off; off = align256(off + (size_t)in_sizes[i] * 2); }
    size_t off_mb   = off; off = align256(off + (size_t)8 * Nn * 4);
    size_t off_ab   = off; off = align256(off + (size_t)8 * Nn * AST * 2);
    size_t off_q    = off; off = align256(off + (size_t)Bn * Nn * 256 * 2);
    size_t off_k    = off; off = align256(off + (size_t)Bn * Nn * 256 * 2);
    size_t off_v    = off; off = align256(off + (size_t)Bn * Nn * DHn * 2);
    size_t off_vt   = off; off = align256(off + (size_t)Bn * DHn * AST * 2);
    size_t off_o    = off; off = align256(off + (size_t)Bn * Nn * DHn * 2);
    size_t off_xt   = off; off = align256(off + (size_t)Bn * Nn * CIN * 2);
    size_t off_wqkv = off; off = align256(off + (size_t)1536 * CIN * 2);
    size_t off_al   = off; off = align256(off + (size_t)1536 * 4);
    size_t off_be   = off; off = align256(off + (size_t)1536 * 4);
    size_t off_wvlt = off; off = align256(off + (size_t)9 * 1024 * 2);
    size_t base = off;

    const size_t attn_per_b = (size_t)8 * Nn * AST * 2;
    int GB = 0;
    const int cand[4] = {8, 4, 2, 1};
    for (int ci = 0; ci < 4; ++ci) {
        if (base + (size_t)cand[ci] * attn_per_b + 512 <= ws_size) { GB = cand[ci]; break; }
    }
    if (!GB) return; // ws too small -> zeros out (diagnostic absmax ~17.4)

    size_t off_attn = base;

    int*  flag = (int*)(ws + off_flag);
    bf16* Pb[26];
    for (int i = 0; i < 26; ++i) Pb[i] = (bf16*)(ws + p_off[i]);
    float* mb    = (float*)(ws + off_mb);
    bf16* abfull = (bf16*)(ws + off_ab);
    bf16* qbuf  = (bf16*)(ws + off_q);
    bf16* kbuf  = (bf16*)(ws + off_k);
    bf16* vbuf  = (bf16*)(ws + off_v);
    bf16* vt    = (bf16*)(ws + off_vt);
    bf16* obuf  = (bf16*)(ws + off_o);
    bf16* xt    = (bf16*)(ws + off_xt);
    bf16* wqkv  = (bf16*)(ws + off_wqkv);
    float* alf  = (float*)(ws + off_al);
    float* bef  = (float*)(ws + off_be);
    bf16* wvlt  = (bf16*)(ws + off_wvlt);
    bf16* attn  = (bf16*)(ws + off_attn);
    const int* idxs = (const int*)d_in[26];

    k_detect<<<1, 64, 0, stream>>>((const unsigned*)d_in[0], flag);

    PtrArgs pa;
    for (int i = 0; i < 26; ++i) pa.p[i] = d_in[i];
    k_prep<<<dim3(288, 4), 256, 0, stream>>>(pa, wqkv, alf, bef, mb, wvlt, flag);

    const int cidx[10] = {14, 15, 16, 17, 19, 20, 21, 22, 23, 24};
    ConvArgs ca;
    for (int i = 0; i < 10; ++i) {
        ca.src[i] = d_in[cidx[i]];
        ca.dstoff[i] = p_off[cidx[i]];
        ca.n[i] = in_sizes[cidx[i]];
    }
    k_convb_all<<<dim3(64, 10), 256, 0, stream>>>(ca, ws, flag);

    bf16 *bvl = Pb[14], *vls = Pb[15], *vlb = Pb[16],
         *W1 = Pb[17], *W2 = Pb[19], *b2v = Pb[20],
         *Wp = Pb[21], *bp = Pb[22], *ps = Pb[23], *pb = Pb[24];

    k_xt<<<dim3(25, 12, 8), 256, 0, stream>>>(d_in[0], xt, flag);
    k_abfull<<<dim3(392), 256, 0, stream>>>(mb, idxs, abfull);

    k_proj_m<<<dim3(7, 12, 8), 256, 0, stream>>>(xt, wqkv, alf, bef, qbuf, kbuf, vbuf);
    k_vt<<<dim3(25, 32, 8), 256, 0, stream>>>(vbuf, vt);

    for (int bi0 = 0; bi0 < Bn; bi0 += GB) {
        k_logits_raw<<<dim3(7, 7, GB * 8), 256, 0, stream>>>(qbuf, kbuf, attn, bi0);
        k_softmax_mix<<<dim3(392, GB), 256, 0, stream>>>(attn, abfull, W1, W2, b2v);
        k_pv_m<<<dim3(13, 1, GB * 8), 256, 0, stream>>>(attn, vt, obuf, bi0);
    }

    k_dwconv_add<<<dim3(1, Nn / 2, 8), 256, 0, stream>>>(vbuf, wvlt, bvl, vls, vlb, obuf);
    k_outproj_m<<<dim3(7, 6, 8), 256, 0, stream>>>(Wp, obuf, bp, ps, pb, d_out, flag);
}